// Round 7
// baseline (80.106 us; speedup 1.0000x reference)
//
#include <hip/hip_runtime.h>
#include <hip/hip_bf16.h>
#include <stdint.h>

#define SEQ 4096
#define DM 512
#define NH 8
#define HD 64
#define WIN 65

typedef __attribute__((ext_vector_type(8))) short bf16x8;
typedef __attribute__((ext_vector_type(4))) float f32x4;

#define GLOAD_LDS16(gp, lp)                                                 \
  __builtin_amdgcn_global_load_lds(                                         \
      (const __attribute__((address_space(1))) void*)(gp),                  \
      (__attribute__((address_space(3))) void*)(lp), 16, 0, 0)

__device__ __forceinline__ unsigned short f2bf(float f) {
  unsigned int u = __float_as_uint(f);
  u += 0x7FFFu + ((u >> 16) & 1u);
  return (unsigned short)(u >> 16);
}

// ---- fused prep: convert x (f32->bf16) and transpose+convert all 4 W ----
__global__ __launch_bounds__(256) void prep_kernel(
    const float* __restrict__ x, unsigned short* __restrict__ xb,
    const float* __restrict__ w0, const float* __restrict__ w1,
    const float* __restrict__ w2, const float* __restrict__ w3,
    unsigned short* __restrict__ wt) {
  __shared__ float tl[64][65];
  const int bid = blockIdx.x;
  const int t = threadIdx.x;
  if (bid < 4096) {
    const int i = bid * 256 + t;
    float4 v = ((const float4*)x)[i];
    ushort4 o;
    o.x = f2bf(v.x); o.y = f2bf(v.y); o.z = f2bf(v.z); o.w = f2bf(v.w);
    ((ushort4*)xb)[i] = o;
    return;
  }
  const int wtid = bid - 4096;          // [0,256)
  const int z = wtid >> 6;
  const int rem = wtid & 63;
  const int k0 = (rem >> 3) * 64;
  const int n0 = (rem & 7) * 64;
  const float* W = (z == 0) ? w0 : (z == 1) ? w1 : (z == 2) ? w2 : w3;
  unsigned short* o = wt + (size_t)z * 262144;
#pragma unroll
  for (int i = 0; i < 16; ++i) {
    int idx = t + i * 256;
    int r = idx >> 6, c = idx & 63;
    tl[c][r] = W[(size_t)(k0 + r) * 512 + n0 + c];
  }
  __syncthreads();
#pragma unroll
  for (int i = 0; i < 16; ++i) {
    int idx = t + i * 256;
    int r = idx >> 6, c = idx & 63;
    o[(size_t)(n0 + r) * 512 + k0 + c] = f2bf(tl[r][c]);
  }
}

// ---- bf16 MFMA GEMM, global_load_lds(16B), BK=64 via dual [BM][32] buffers ----
// Operand-swapped MFMA (C^T layout) for q/k and Wo so epilogue stores are
// vectorized along the feature dim; z==2 (vt) keeps normal orientation.
// MODE 0 (grid 768, BM=128): bm = bid&63, nz = bid>>6.
// MODE 1 (grid 512, BM=64):  bm = bid&127, bn = bid>>7.
template <int MODE>
__global__ __launch_bounds__(256) void gemm_kernel(
    const unsigned short* __restrict__ A,
    const unsigned short* __restrict__ wt,
    const float* __restrict__ b0, const float* __restrict__ b1, const float* __restrict__ b2,
    void* __restrict__ outp) {
  constexpr int BM = MODE ? 64 : 128;
  constexpr int MI = MODE ? 2 : 4;
  const int bid = blockIdx.x;
  int bm, bn, z;
  if (MODE == 0) {
    bm = bid & 63;
    const int nz = bid >> 6;      // 0..11
    z = nz >> 2;
    bn = nz & 3;
  } else {
    bm = bid & 127;
    bn = bid >> 7;
    z = 0;
  }
  const int bm0 = bm * BM;
  const int bn0 = bn * 128;
  const unsigned short* W = wt + (size_t)z * 262144;
  const float* bias = (MODE == 0) ? ((z == 0) ? b0 : (z == 1) ? b1 : b2) : b0;

  __shared__ unsigned short As0[BM * 32];
  __shared__ unsigned short As1[BM * 32];
  __shared__ unsigned short Bs0[128 * 32];
  __shared__ unsigned short Bs1[128 * 32];

  const int t = threadIdx.x;
  const int lane = t & 63;
  const int wv = t >> 6;
  const int wr = wv >> 1, wc = wv & 1;
  const int l15 = lane & 15, l4 = lane >> 4;

  const int cr = lane >> 2;          // row within 16-row chunk
  const int cc = (lane & 3) * 8;     // col halves within 32

  const unsigned short* ApA;
  unsigned short *lA0a, *lA1a, *lA0b = nullptr, *lA1b = nullptr;
  const unsigned short* ApB = nullptr;
  if (MODE == 0) {
    ApA = A + (size_t)(bm0 + wv * 32 + cr) * 512 + cc;
    ApB = ApA + (size_t)16 * 512;
    lA0a = &As0[(wv * 2 + 0) * 512];
    lA0b = &As0[(wv * 2 + 1) * 512];
    lA1a = &As1[(wv * 2 + 0) * 512];
    lA1b = &As1[(wv * 2 + 1) * 512];
  } else {
    ApA = A + (size_t)(bm0 + wv * 16 + cr) * 512 + cc;
    lA0a = &As0[wv * 512];
    lA1a = &As1[wv * 512];
  }
  const unsigned short* BpA = W + (size_t)(bn0 + wv * 32 + cr) * 512 + cc;
  const unsigned short* BpB = BpA + (size_t)16 * 512;
  unsigned short* lB0a = &Bs0[(wv * 2 + 0) * 512];
  unsigned short* lB0b = &Bs0[(wv * 2 + 1) * 512];
  unsigned short* lB1a = &Bs1[(wv * 2 + 0) * 512];
  unsigned short* lB1b = &Bs1[(wv * 2 + 1) * 512];

  // swapped: C^T orientation (features on (l4,j), tokens on l15)
  const bool swapped = (MODE == 1) || (z != 2);

  f32x4 acc[MI][4];
#pragma unroll
  for (int i = 0; i < MI; ++i)
#pragma unroll
    for (int j = 0; j < 4; ++j) acc[i][j] = (f32x4){0.f, 0.f, 0.f, 0.f};

  for (int kt = 0; kt < 512; kt += 64) {
    __syncthreads();
    GLOAD_LDS16(ApA + kt, lA0a);
    GLOAD_LDS16(ApA + kt + 32, lA1a);
    if (MODE == 0) {
      GLOAD_LDS16(ApB + kt, lA0b);
      GLOAD_LDS16(ApB + kt + 32, lA1b);
    }
    GLOAD_LDS16(BpA + kt, lB0a);
    GLOAD_LDS16(BpA + kt + 32, lB1a);
    GLOAD_LDS16(BpB + kt, lB0b);
    GLOAD_LDS16(BpB + kt + 32, lB1b);
    __syncthreads();
    bf16x8 af0[MI], af1[MI], bf0[4], bf1[4];
#pragma unroll
    for (int mi = 0; mi < MI; ++mi) {
      const int r = (MODE ? wr * 32 : wr * 64) + mi * 16 + l15;
      af0[mi] = *(const bf16x8*)&As0[r * 32 + l4 * 8];
      af1[mi] = *(const bf16x8*)&As1[r * 32 + l4 * 8];
    }
#pragma unroll
    for (int ni = 0; ni < 4; ++ni) {
      const int r = wc * 64 + ni * 16 + l15;
      bf0[ni] = *(const bf16x8*)&Bs0[r * 32 + l4 * 8];
      bf1[ni] = *(const bf16x8*)&Bs1[r * 32 + l4 * 8];
    }
    if (swapped) {
#pragma unroll
      for (int mi = 0; mi < MI; ++mi)
#pragma unroll
        for (int ni = 0; ni < 4; ++ni) {
          acc[mi][ni] = __builtin_amdgcn_mfma_f32_16x16x32_bf16(bf0[ni], af0[mi], acc[mi][ni], 0, 0, 0);
          acc[mi][ni] = __builtin_amdgcn_mfma_f32_16x16x32_bf16(bf1[ni], af1[mi], acc[mi][ni], 0, 0, 0);
        }
    } else {
#pragma unroll
      for (int mi = 0; mi < MI; ++mi)
#pragma unroll
        for (int ni = 0; ni < 4; ++ni) {
          acc[mi][ni] = __builtin_amdgcn_mfma_f32_16x16x32_bf16(af0[mi], bf0[ni], acc[mi][ni], 0, 0, 0);
          acc[mi][ni] = __builtin_amdgcn_mfma_f32_16x16x32_bf16(af1[mi], bf1[ni], acc[mi][ni], 0, 0, 0);
        }
    }
  }

  const float sc = (MODE == 0 && z == 0) ? 0.125f : 1.0f;
#pragma unroll
  for (int mi = 0; mi < MI; ++mi) {
#pragma unroll
    for (int ni = 0; ni < 4; ++ni) {
      if (MODE == 0 && z == 2) {
        // vt path (unswapped): tokens on (l4,j), features on l15
        const int gn = bn0 + wc * 64 + ni * 16 + l15;
        const float bb = bias[gn];
        ushort4 o4;
        o4.x = f2bf(acc[mi][ni][0] + bb);
        o4.y = f2bf(acc[mi][ni][1] + bb);
        o4.z = f2bf(acc[mi][ni][2] + bb);
        o4.w = f2bf(acc[mi][ni][3] + bb);
        const int gm0 = bm0 + wr * 64 + mi * 16 + l4 * 4;
        const int b = gm0 >> 12;
        const int nn = gm0 & 4095;
        const int h = gn >> 6;
        const int dd = gn & 63;
        unsigned short* op = (unsigned short*)outp + (size_t)2 * 4194304;
        *(ushort4*)&op[((size_t)(b * NH + h) * HD + dd) * SEQ + nn] = o4;
      } else if (MODE == 0) {
        // q/k path (swapped): features on (l4,j), token on l15 -> ushort4 along d
        const int gm = bm0 + wr * 64 + mi * 16 + l15;
        const int b = gm >> 12;
        const int nn = gm & 4095;
        const int gn0 = bn0 + wc * 64 + ni * 16 + l4 * 4;
        const int h = gn0 >> 6;
        const int dd = gn0 & 63;
        ushort4 o4;
        o4.x = f2bf((acc[mi][ni][0] + bias[gn0 + 0]) * sc);
        o4.y = f2bf((acc[mi][ni][1] + bias[gn0 + 1]) * sc);
        o4.z = f2bf((acc[mi][ni][2] + bias[gn0 + 2]) * sc);
        o4.w = f2bf((acc[mi][ni][3] + bias[gn0 + 3]) * sc);
        unsigned short* op = (unsigned short*)outp + (size_t)z * 4194304;
        *(ushort4*)&op[(((size_t)(b * NH + h) * SEQ) + nn) * HD + dd] = o4;
      } else {
        // Wo path (swapped): float4 store along features
        const int gm = bm0 + wr * 32 + mi * 16 + l15;
        const int gn0 = bn0 + wc * 64 + ni * 16 + l4 * 4;
        const float4 bb4 = *(const float4*)&bias[gn0];
        float4 o;
        o.x = acc[mi][ni][0] + bb4.x;
        o.y = acc[mi][ni][1] + bb4.y;
        o.z = acc[mi][ni][2] + bb4.z;
        o.w = acc[mi][ni][3] + bb4.w;
        float* op = (float*)outp;
        *(float4*)&op[(size_t)gm * 512 + gn0] = o;
      }
    }
  }
}

// ---- MFMA local attention ----
// 512 threads = 8 waves, wave = 16 queries. QK^T banded strip (10 MFMAs),
// softmax in C-frag registers, normalized P -> f32 LDS strip (stride 100),
// coalesced attn_out stores, PV swapped (12 MFMAs) -> ushort4 ctxb stores.
__global__ __launch_bounds__(512) void attn_kernel(
    const unsigned short* __restrict__ qb, const unsigned short* __restrict__ kb,
    const unsigned short* __restrict__ vt,
    float* __restrict__ attn_out, unsigned short* __restrict__ ctxb) {
  __shared__ float P[8][16][100];     // cols 0..79 = scores, 80..95 zero pad
  const int t = threadIdx.x;
  const int lane = t & 63;
  const int wv = t >> 6;
  const int l15 = lane & 15;
  const int g = lane >> 4;
  const int bh = blockIdx.y;
  const int n0 = blockIdx.x * 128;
  const int q0 = n0 + wv * 16;
  const size_t qkbase = (size_t)bh * SEQ * HD;

  // ---- QK^T: S[i][c], c in [0,80), k-row = q0-32+c  (q pre-scaled by 1/8) ----
  bf16x8 aq[2];
#pragma unroll
  for (int kc = 0; kc < 2; ++kc)
    aq[kc] = *(const bf16x8*)&qb[qkbase + (size_t)(q0 + l15) * HD + kc * 32 + g * 8];

  f32x4 accs[5];
#pragma unroll
  for (int tt = 0; tt < 5; ++tt) accs[tt] = (f32x4){0.f, 0.f, 0.f, 0.f};

#pragma unroll
  for (int tt = 0; tt < 5; ++tt) {
    const int krow = q0 - 32 + tt * 16 + l15;
    bf16x8 bk0 = (bf16x8){0, 0, 0, 0, 0, 0, 0, 0};
    bf16x8 bk1 = bk0;
    if (krow >= 0 && krow < SEQ) {
      bk0 = *(const bf16x8*)&kb[qkbase + (size_t)krow * HD + g * 8];
      bk1 = *(const bf16x8*)&kb[qkbase + (size_t)krow * HD + 32 + g * 8];
    }
    accs[tt] = __builtin_amdgcn_mfma_f32_16x16x32_bf16(aq[0], bk0, accs[tt], 0, 0, 0);
    accs[tt] = __builtin_amdgcn_mfma_f32_16x16x32_bf16(aq[1], bk1, accs[tt], 0, 0, 0);
  }

  // ---- softmax over w = c - i in [0,64]; C layout: col = 16tt+l15, row = 4g+j ----
#pragma unroll
  for (int tt = 0; tt < 5; ++tt)
#pragma unroll
    for (int j = 0; j < 4; ++j) {
      const int w = tt * 16 + l15 - (4 * g + j);
      if (!(w >= 0 && w <= 64)) accs[tt][j] = -3.0e38f;
    }
  float mj[4], invj[4];
#pragma unroll
  for (int j = 0; j < 4; ++j) {
    float m = fmaxf(fmaxf(fmaxf(accs[0][j], accs[1][j]), fmaxf(accs[2][j], accs[3][j])), accs[4][j]);
#pragma unroll
    for (int o = 8; o; o >>= 1) m = fmaxf(m, __shfl_xor(m, o));
    mj[j] = m;
  }
#pragma unroll
  for (int tt = 0; tt < 5; ++tt)
#pragma unroll
    for (int j = 0; j < 4; ++j)
      accs[tt][j] = (accs[tt][j] > -1.0e38f) ? __expf(accs[tt][j] - mj[j]) : 0.f;
#pragma unroll
  for (int j = 0; j < 4; ++j) {
    float s = accs[0][j] + accs[1][j] + accs[2][j] + accs[3][j] + accs[4][j];
#pragma unroll
    for (int o = 8; o; o >>= 1) s += __shfl_xor(s, o);
    invj[j] = 1.f / s;
  }
  // normalized P -> LDS (cols 0..79), zero pad cols 80..95
#pragma unroll
  for (int tt = 0; tt < 5; ++tt)
#pragma unroll
    for (int j = 0; j < 4; ++j)
      P[wv][4 * g + j][tt * 16 + l15] = accs[tt][j] * invj[j];
  {
    const int r = lane >> 2, c4 = lane & 3;
#pragma unroll
    for (int jj = 0; jj < 4; ++jj) P[wv][r][80 + c4 + 4 * jj] = 0.f;
  }

  // ---- attn_out stores: row r covers w=0..64 -> P cols r..r+64 ----
  {
    const int r = lane >> 2, c4 = lane & 3;
    const size_t abase = (size_t)bh * SEQ;
    float* aor = &attn_out[(abase + q0 + r) * WIN];
    const float* pr = &P[wv][r][r];
#pragma unroll
    for (int jj = 0; jj < 16; ++jj) aor[c4 + 4 * jj] = pr[c4 + 4 * jj];
    if (c4 == 0) aor[64] = pr[64];
  }

  // ---- PV (swapped): ctx^T, d on (g,j), query on l15 -> ushort4 stores ----
  f32x4 accc[4];
#pragma unroll
  for (int dt = 0; dt < 4; ++dt) accc[dt] = (f32x4){0.f, 0.f, 0.f, 0.f};
#pragma unroll
  for (int kc = 0; kc < 3; ++kc) {
    const float4 p0 = *(const float4*)&P[wv][l15][kc * 32 + g * 8];
    const float4 p1 = *(const float4*)&P[wv][l15][kc * 32 + g * 8 + 4];
    bf16x8 pa;
    pa[0] = (short)f2bf(p0.x); pa[1] = (short)f2bf(p0.y);
    pa[2] = (short)f2bf(p0.z); pa[3] = (short)f2bf(p0.w);
    pa[4] = (short)f2bf(p1.x); pa[5] = (short)f2bf(p1.y);
    pa[6] = (short)f2bf(p1.z); pa[7] = (short)f2bf(p1.w);
    const int nb = q0 - 32 + kc * 32 + g * 8;   // multiple of 8: chunk all-in or all-out
    const bool inr = (nb >= 0 && nb < SEQ);
#pragma unroll
    for (int dt = 0; dt < 4; ++dt) {
      bf16x8 bv = (bf16x8){0, 0, 0, 0, 0, 0, 0, 0};
      if (inr) bv = *(const bf16x8*)&vt[((size_t)bh * HD + dt * 16 + l15) * SEQ + nb];
      accc[dt] = __builtin_amdgcn_mfma_f32_16x16x32_bf16(bv, pa, accc[dt], 0, 0, 0);
    }
  }
  const int b = bh >> 3, h = bh & 7;
  {
    unsigned short* cp = &ctxb[((size_t)(b * SEQ + q0 + l15)) * DM + h * HD];
#pragma unroll
    for (int dt = 0; dt < 4; ++dt) {
      ushort4 o4;
      o4.x = f2bf(accc[dt][0]);
      o4.y = f2bf(accc[dt][1]);
      o4.z = f2bf(accc[dt][2]);
      o4.w = f2bf(accc[dt][3]);
      *(ushort4*)&cp[dt * 16 + g * 4] = o4;
    }
  }
}

extern "C" void kernel_launch(void* const* d_in, const int* in_sizes, int n_in,
                              void* d_out, int out_size, void* d_ws, size_t ws_size,
                              hipStream_t stream) {
  const float* x  = (const float*)d_in[0];
  const float* Wq = (const float*)d_in[1];
  const float* Wk = (const float*)d_in[2];
  const float* Wv = (const float*)d_in[3];
  const float* Wo = (const float*)d_in[4];
  const float* bq = (const float*)d_in[5];
  const float* bk = (const float*)d_in[6];
  const float* bv = (const float*)d_in[7];
  const float* bo = (const float*)d_in[8];

  float* out = (float*)d_out;                        // (B, N, 512) f32
  float* attn_out = out + (size_t)8192 * 512;        // (B, H, N, 65) f32

  char* ws = (char*)d_ws;
  unsigned short* xb   = (unsigned short*)ws;                       // 8,388,608 B
  unsigned short* wt   = (unsigned short*)(ws + 8388608);           // 2,097,152 B
  unsigned short* qkv  = (unsigned short*)(ws + 10485760);          // 25,165,824 B
  unsigned short* ctxb = (unsigned short*)(ws + 35651584);          // 8,388,608 B

  prep_kernel<<<dim3(4352), dim3(256), 0, stream>>>(x, xb, Wq, Wk, Wv, Wo, wt);
  gemm_kernel<0><<<dim3(768), dim3(256), 0, stream>>>(xb, wt, bq, bk, bv, (void*)qkv);
  attn_kernel<<<dim3(32, 16), dim3(512), 0, stream>>>(
      qkv, qkv + 4194304, qkv + 8388608, attn_out, ctxb);
  gemm_kernel<1><<<dim3(512), dim3(256), 0, stream>>>(ctxb, wt + 3 * 262144, bo, nullptr, nullptr, (void*)out);
}

// Round 8
// 70.647 us; speedup vs baseline: 1.1339x; 1.1339x over previous
//
#include <hip/hip_runtime.h>
#include <hip/hip_bf16.h>
#include <stdint.h>

#define SEQ 4096
#define DM 512
#define NH 8
#define HD 64
#define WIN 65

typedef __attribute__((ext_vector_type(8))) short bf16x8;
typedef __attribute__((ext_vector_type(4))) float f32x4;

#define GLOAD_LDS16(gp, lp)                                                 \
  __builtin_amdgcn_global_load_lds(                                         \
      (const __attribute__((address_space(1))) void*)(gp),                  \
      (__attribute__((address_space(3))) void*)(lp), 16, 0, 0)

__device__ __forceinline__ unsigned short f2bf(float f) {
  unsigned int u = __float_as_uint(f);
  u += 0x7FFFu + ((u >> 16) & 1u);
  return (unsigned short)(u >> 16);
}

// ---- fused prep: convert x (f32->bf16) and transpose+convert all 4 W ----
__global__ __launch_bounds__(256) void prep_kernel(
    const float* __restrict__ x, unsigned short* __restrict__ xb,
    const float* __restrict__ w0, const float* __restrict__ w1,
    const float* __restrict__ w2, const float* __restrict__ w3,
    unsigned short* __restrict__ wt) {
  __shared__ float tl[64][65];
  const int bid = blockIdx.x;
  const int t = threadIdx.x;
  if (bid < 4096) {
    const int i = bid * 256 + t;
    float4 v = ((const float4*)x)[i];
    ushort4 o;
    o.x = f2bf(v.x); o.y = f2bf(v.y); o.z = f2bf(v.z); o.w = f2bf(v.w);
    ((ushort4*)xb)[i] = o;
    return;
  }
  const int wtid = bid - 4096;          // [0,256)
  const int z = wtid >> 6;
  const int rem = wtid & 63;
  const int k0 = (rem >> 3) * 64;
  const int n0 = (rem & 7) * 64;
  const float* W = (z == 0) ? w0 : (z == 1) ? w1 : (z == 2) ? w2 : w3;
  unsigned short* o = wt + (size_t)z * 262144;
#pragma unroll
  for (int i = 0; i < 16; ++i) {
    int idx = t + i * 256;
    int r = idx >> 6, c = idx & 63;
    tl[c][r] = W[(size_t)(k0 + r) * 512 + n0 + c];
  }
  __syncthreads();
#pragma unroll
  for (int i = 0; i < 16; ++i) {
    int idx = t + i * 256;
    int r = idx >> 6, c = idx & 63;
    o[(size_t)(n0 + r) * 512 + k0 + c] = f2bf(tl[r][c]);
  }
}

// ---- bf16 MFMA GEMM, global_load_lds(16B), BK=64 via dual [BM][32] buffers ----
// Dual buffers keep the dense 64B-row conflict-free layout; 8 K-iterations.
// MODE 0 (grid 768, BM=128): bm = bid&63, nz = bid>>6; q (scaled 1/8), k -> (B*H,N,64);
//         v -> transposed (B*H,64,N).
// MODE 1 (grid 512, BM=64):  bm = bid&127, bn = bid>>7; Wo; out f32 (B*N,512).
template <int MODE>
__global__ __launch_bounds__(256) void gemm_kernel(
    const unsigned short* __restrict__ A,
    const unsigned short* __restrict__ wt,
    const float* __restrict__ b0, const float* __restrict__ b1, const float* __restrict__ b2,
    void* __restrict__ outp) {
  constexpr int BM = MODE ? 64 : 128;
  constexpr int MI = MODE ? 2 : 4;
  const int bid = blockIdx.x;
  int bm, bn, z;
  if (MODE == 0) {
    bm = bid & 63;
    const int nz = bid >> 6;      // 0..11
    z = nz >> 2;
    bn = nz & 3;
  } else {
    bm = bid & 127;
    bn = bid >> 7;
    z = 0;
  }
  const int bm0 = bm * BM;
  const int bn0 = bn * 128;
  const unsigned short* W = wt + (size_t)z * 262144;
  const float* bias = (MODE == 0) ? ((z == 0) ? b0 : (z == 1) ? b1 : b2) : b0;

  __shared__ unsigned short As0[BM * 32];
  __shared__ unsigned short As1[BM * 32];
  __shared__ unsigned short Bs0[128 * 32];
  __shared__ unsigned short Bs1[128 * 32];

  const int t = threadIdx.x;
  const int lane = t & 63;
  const int wv = t >> 6;
  const int wr = wv >> 1, wc = wv & 1;
  const int l15 = lane & 15, l4 = lane >> 4;

  const int cr = lane >> 2;          // row within 16-row chunk
  const int cc = (lane & 3) * 8;     // col halves within 32

  const unsigned short* ApA;
  unsigned short *lA0a, *lA1a, *lA0b = nullptr, *lA1b = nullptr;
  const unsigned short* ApB = nullptr;
  if (MODE == 0) {
    ApA = A + (size_t)(bm0 + wv * 32 + cr) * 512 + cc;
    ApB = ApA + (size_t)16 * 512;
    lA0a = &As0[(wv * 2 + 0) * 512];
    lA0b = &As0[(wv * 2 + 1) * 512];
    lA1a = &As1[(wv * 2 + 0) * 512];
    lA1b = &As1[(wv * 2 + 1) * 512];
  } else {
    ApA = A + (size_t)(bm0 + wv * 16 + cr) * 512 + cc;
    lA0a = &As0[wv * 512];
    lA1a = &As1[wv * 512];
  }
  const unsigned short* BpA = W + (size_t)(bn0 + wv * 32 + cr) * 512 + cc;
  const unsigned short* BpB = BpA + (size_t)16 * 512;
  unsigned short* lB0a = &Bs0[(wv * 2 + 0) * 512];
  unsigned short* lB0b = &Bs0[(wv * 2 + 1) * 512];
  unsigned short* lB1a = &Bs1[(wv * 2 + 0) * 512];
  unsigned short* lB1b = &Bs1[(wv * 2 + 1) * 512];

  f32x4 acc[MI][4];
#pragma unroll
  for (int i = 0; i < MI; ++i)
#pragma unroll
    for (int j = 0; j < 4; ++j) acc[i][j] = (f32x4){0.f, 0.f, 0.f, 0.f};

  for (int kt = 0; kt < 512; kt += 64) {
    __syncthreads();
    GLOAD_LDS16(ApA + kt, lA0a);
    GLOAD_LDS16(ApA + kt + 32, lA1a);
    if (MODE == 0) {
      GLOAD_LDS16(ApB + kt, lA0b);
      GLOAD_LDS16(ApB + kt + 32, lA1b);
    }
    GLOAD_LDS16(BpA + kt, lB0a);
    GLOAD_LDS16(BpA + kt + 32, lB1a);
    GLOAD_LDS16(BpB + kt, lB0b);
    GLOAD_LDS16(BpB + kt + 32, lB1b);
    __syncthreads();
    bf16x8 af0[MI], af1[MI], bf0[4], bf1[4];
#pragma unroll
    for (int mi = 0; mi < MI; ++mi) {
      const int r = (MODE ? wr * 32 : wr * 64) + mi * 16 + l15;
      af0[mi] = *(const bf16x8*)&As0[r * 32 + l4 * 8];
      af1[mi] = *(const bf16x8*)&As1[r * 32 + l4 * 8];
    }
#pragma unroll
    for (int ni = 0; ni < 4; ++ni) {
      const int r = wc * 64 + ni * 16 + l15;
      bf0[ni] = *(const bf16x8*)&Bs0[r * 32 + l4 * 8];
      bf1[ni] = *(const bf16x8*)&Bs1[r * 32 + l4 * 8];
    }
#pragma unroll
    for (int mi = 0; mi < MI; ++mi)
#pragma unroll
      for (int ni = 0; ni < 4; ++ni) {
        acc[mi][ni] = __builtin_amdgcn_mfma_f32_16x16x32_bf16(af0[mi], bf0[ni], acc[mi][ni], 0, 0, 0);
        acc[mi][ni] = __builtin_amdgcn_mfma_f32_16x16x32_bf16(af1[mi], bf1[ni], acc[mi][ni], 0, 0, 0);
      }
  }

  const float sc = (MODE == 0 && z == 0) ? 0.125f : 1.0f;
#pragma unroll
  for (int mi = 0; mi < MI; ++mi) {
#pragma unroll
    for (int ni = 0; ni < 4; ++ni) {
      const int gn = bn0 + wc * 64 + ni * 16 + l15;
      const float bb = bias[gn];
      if (MODE == 0 && z == 2) {
        ushort4 o4;
        o4.x = f2bf(acc[mi][ni][0] + bb);
        o4.y = f2bf(acc[mi][ni][1] + bb);
        o4.z = f2bf(acc[mi][ni][2] + bb);
        o4.w = f2bf(acc[mi][ni][3] + bb);
        const int gm0 = bm0 + wr * 64 + mi * 16 + l4 * 4;
        const int b = gm0 >> 12;
        const int nn = gm0 & 4095;
        const int h = gn >> 6;
        const int dd = gn & 63;
        unsigned short* op = (unsigned short*)outp + (size_t)2 * 4194304;
        *(ushort4*)&op[((size_t)(b * NH + h) * HD + dd) * SEQ + nn] = o4;
      } else {
#pragma unroll
        for (int j = 0; j < 4; ++j) {
          const int gm = bm0 + (MODE ? wr * 32 : wr * 64) + mi * 16 + l4 * 4 + j;
          const float val = (acc[mi][ni][j] + bb) * sc;
          if (MODE == 0) {
            const int b = gm >> 12;
            const int nn = gm & 4095;
            const int h = gn >> 6;
            const int dd = gn & 63;
            unsigned short* op = (unsigned short*)outp + (size_t)z * 4194304;
            op[(((size_t)(b * NH + h) * SEQ) + nn) * HD + dd] = f2bf(val);
          } else {
            float* op = (float*)outp;
            op[(size_t)gm * 512 + gn] = val;
          }
        }
      }
    }
  }
}

// ---- MFMA local attention ----
// 256 threads = 4 waves (was 8): LDS 25.6KB, grid 1024 -> 4 blocks/CU for
// more independent QK->softmax->PV chains per CU (latency hiding).
// Per wave: 16 queries. QK^T banded strip (10 MFMAs), softmax in C-frag
// registers, normalized P -> f32 LDS strip (stride 100), coalesced attn_out
// stores, PV (12 MFMAs) vs transposed V.
__global__ __launch_bounds__(256) void attn_kernel(
    const unsigned short* __restrict__ qb, const unsigned short* __restrict__ kb,
    const unsigned short* __restrict__ vt,
    float* __restrict__ attn_out, unsigned short* __restrict__ ctxb) {
  __shared__ float P[4][16][100];     // cols 0..79 = scores, 80..95 zero pad
  const int t = threadIdx.x;
  const int lane = t & 63;
  const int wv = t >> 6;              // 0..3
  const int l15 = lane & 15;
  const int g = lane >> 4;
  const int bh = blockIdx.y;
  const int n0 = blockIdx.x * 64;
  const int q0 = n0 + wv * 16;
  const size_t qkbase = (size_t)bh * SEQ * HD;

  // ---- QK^T: S[i][c], c in [0,80), k-row = q0-32+c  (q pre-scaled by 1/8) ----
  bf16x8 aq[2];
#pragma unroll
  for (int kc = 0; kc < 2; ++kc)
    aq[kc] = *(const bf16x8*)&qb[qkbase + (size_t)(q0 + l15) * HD + kc * 32 + g * 8];

  f32x4 accs[5];
#pragma unroll
  for (int tt = 0; tt < 5; ++tt) accs[tt] = (f32x4){0.f, 0.f, 0.f, 0.f};

#pragma unroll
  for (int tt = 0; tt < 5; ++tt) {
    const int krow = q0 - 32 + tt * 16 + l15;
    bf16x8 bk0 = (bf16x8){0, 0, 0, 0, 0, 0, 0, 0};
    bf16x8 bk1 = bk0;
    if (krow >= 0 && krow < SEQ) {
      bk0 = *(const bf16x8*)&kb[qkbase + (size_t)krow * HD + g * 8];
      bk1 = *(const bf16x8*)&kb[qkbase + (size_t)krow * HD + 32 + g * 8];
    }
    accs[tt] = __builtin_amdgcn_mfma_f32_16x16x32_bf16(aq[0], bk0, accs[tt], 0, 0, 0);
    accs[tt] = __builtin_amdgcn_mfma_f32_16x16x32_bf16(aq[1], bk1, accs[tt], 0, 0, 0);
  }

  // ---- softmax over w = c - i in [0,64]; C layout: col = 16tt+l15, row = 4g+j ----
#pragma unroll
  for (int tt = 0; tt < 5; ++tt)
#pragma unroll
    for (int j = 0; j < 4; ++j) {
      const int w = tt * 16 + l15 - (4 * g + j);
      if (!(w >= 0 && w <= 64)) accs[tt][j] = -3.0e38f;
    }
  float mj[4], invj[4];
#pragma unroll
  for (int j = 0; j < 4; ++j) {
    float m = fmaxf(fmaxf(fmaxf(accs[0][j], accs[1][j]), fmaxf(accs[2][j], accs[3][j])), accs[4][j]);
#pragma unroll
    for (int o = 8; o; o >>= 1) m = fmaxf(m, __shfl_xor(m, o));
    mj[j] = m;
  }
#pragma unroll
  for (int tt = 0; tt < 5; ++tt)
#pragma unroll
    for (int j = 0; j < 4; ++j)
      accs[tt][j] = (accs[tt][j] > -1.0e38f) ? __expf(accs[tt][j] - mj[j]) : 0.f;
#pragma unroll
  for (int j = 0; j < 4; ++j) {
    float s = accs[0][j] + accs[1][j] + accs[2][j] + accs[3][j] + accs[4][j];
#pragma unroll
    for (int o = 8; o; o >>= 1) s += __shfl_xor(s, o);
    invj[j] = 1.f / s;
  }
  // normalized P -> LDS (cols 0..79), zero pad cols 80..95
#pragma unroll
  for (int tt = 0; tt < 5; ++tt)
#pragma unroll
    for (int j = 0; j < 4; ++j)
      P[wv][4 * g + j][tt * 16 + l15] = accs[tt][j] * invj[j];
  {
    const int r = lane >> 2, c4 = lane & 3;
#pragma unroll
    for (int jj = 0; jj < 4; ++jj) P[wv][r][80 + c4 + 4 * jj] = 0.f;
  }

  // ---- attn_out stores: row r covers w=0..64 -> P cols r..r+64 ----
  {
    const int r = lane >> 2, c4 = lane & 3;
    const size_t abase = (size_t)bh * SEQ;
    float* aor = &attn_out[(abase + q0 + r) * WIN];
    const float* pr = &P[wv][r][r];
#pragma unroll
    for (int jj = 0; jj < 16; ++jj) aor[c4 + 4 * jj] = pr[c4 + 4 * jj];
    if (c4 == 0) aor[64] = pr[64];
  }

  // ---- PV: ctx[i][d] = sum_c P[i][c] * V[q0-32+c][d], via VT (bh,d,n) ----
  f32x4 accc[4];
#pragma unroll
  for (int dt = 0; dt < 4; ++dt) accc[dt] = (f32x4){0.f, 0.f, 0.f, 0.f};
#pragma unroll
  for (int kc = 0; kc < 3; ++kc) {
    const float4 p0 = *(const float4*)&P[wv][l15][kc * 32 + g * 8];
    const float4 p1 = *(const float4*)&P[wv][l15][kc * 32 + g * 8 + 4];
    bf16x8 pa;
    pa[0] = (short)f2bf(p0.x); pa[1] = (short)f2bf(p0.y);
    pa[2] = (short)f2bf(p0.z); pa[3] = (short)f2bf(p0.w);
    pa[4] = (short)f2bf(p1.x); pa[5] = (short)f2bf(p1.y);
    pa[6] = (short)f2bf(p1.z); pa[7] = (short)f2bf(p1.w);
    const int nb = q0 - 32 + kc * 32 + g * 8;   // multiple of 8: chunk all-in or all-out
    const bool inr = (nb >= 0 && nb < SEQ);
#pragma unroll
    for (int dt = 0; dt < 4; ++dt) {
      bf16x8 bv = (bf16x8){0, 0, 0, 0, 0, 0, 0, 0};
      if (inr) bv = *(const bf16x8*)&vt[((size_t)bh * HD + dt * 16 + l15) * SEQ + nb];
      accc[dt] = __builtin_amdgcn_mfma_f32_16x16x32_bf16(pa, bv, accc[dt], 0, 0, 0);
    }
  }
  const int b = bh >> 3, h = bh & 7;
#pragma unroll
  for (int dt = 0; dt < 4; ++dt)
#pragma unroll
    for (int j = 0; j < 4; ++j)
      ctxb[((size_t)(b * SEQ + q0 + 4 * g + j)) * DM + h * HD + dt * 16 + l15] = f2bf(accc[dt][j]);
}

extern "C" void kernel_launch(void* const* d_in, const int* in_sizes, int n_in,
                              void* d_out, int out_size, void* d_ws, size_t ws_size,
                              hipStream_t stream) {
  const float* x  = (const float*)d_in[0];
  const float* Wq = (const float*)d_in[1];
  const float* Wk = (const float*)d_in[2];
  const float* Wv = (const float*)d_in[3];
  const float* Wo = (const float*)d_in[4];
  const float* bq = (const float*)d_in[5];
  const float* bk = (const float*)d_in[6];
  const float* bv = (const float*)d_in[7];
  const float* bo = (const float*)d_in[8];

  float* out = (float*)d_out;                        // (B, N, 512) f32
  float* attn_out = out + (size_t)8192 * 512;        // (B, H, N, 65) f32

  char* ws = (char*)d_ws;
  unsigned short* xb   = (unsigned short*)ws;                       // 8,388,608 B
  unsigned short* wt   = (unsigned short*)(ws + 8388608);           // 2,097,152 B
  unsigned short* qkv  = (unsigned short*)(ws + 10485760);          // 25,165,824 B
  unsigned short* ctxb = (unsigned short*)(ws + 35651584);          // 8,388,608 B

  prep_kernel<<<dim3(4352), dim3(256), 0, stream>>>(x, xb, Wq, Wk, Wv, Wo, wt);
  gemm_kernel<0><<<dim3(768), dim3(256), 0, stream>>>(xb, wt, bq, bk, bv, (void*)qkv);
  attn_kernel<<<dim3(64, 16), dim3(256), 0, stream>>>(
      qkv, qkv + 4194304, qkv + 8388608, attn_out, ctxb);
  gemm_kernel<1><<<dim3(512), dim3(256), 0, stream>>>(ctxb, wt + 3 * 262144, bo, nullptr, nullptr, (void*)out);
}

// Round 9
// 67.716 us; speedup vs baseline: 1.1830x; 1.0433x over previous
//
#include <hip/hip_runtime.h>
#include <hip/hip_bf16.h>
#include <stdint.h>

#define SEQ 4096
#define DM 512
#define NH 8
#define HD 64
#define WIN 65

typedef __attribute__((ext_vector_type(8))) short bf16x8;
typedef __attribute__((ext_vector_type(4))) float f32x4;

#define GLOAD_LDS16(gp, lp)                                                 \
  __builtin_amdgcn_global_load_lds(                                         \
      (const __attribute__((address_space(1))) void*)(gp),                  \
      (__attribute__((address_space(3))) void*)(lp), 16, 0, 0)

__device__ __forceinline__ unsigned short f2bf(float f) {
  unsigned int u = __float_as_uint(f);
  u += 0x7FFFu + ((u >> 16) & 1u);
  return (unsigned short)(u >> 16);
}

// ---- fused prep: convert x (f32->bf16) and transpose+convert all 4 W ----
__global__ __launch_bounds__(256) void prep_kernel(
    const float* __restrict__ x, unsigned short* __restrict__ xb,
    const float* __restrict__ w0, const float* __restrict__ w1,
    const float* __restrict__ w2, const float* __restrict__ w3,
    unsigned short* __restrict__ wt) {
  __shared__ float tl[64][65];
  const int bid = blockIdx.x;
  const int t = threadIdx.x;
  if (bid < 4096) {
    const int i = bid * 256 + t;
    float4 v = ((const float4*)x)[i];
    ushort4 o;
    o.x = f2bf(v.x); o.y = f2bf(v.y); o.z = f2bf(v.z); o.w = f2bf(v.w);
    ((ushort4*)xb)[i] = o;
    return;
  }
  const int wtid = bid - 4096;          // [0,256)
  const int z = wtid >> 6;
  const int rem = wtid & 63;
  const int k0 = (rem >> 3) * 64;
  const int n0 = (rem & 7) * 64;
  const float* W = (z == 0) ? w0 : (z == 1) ? w1 : (z == 2) ? w2 : w3;
  unsigned short* o = wt + (size_t)z * 262144;
#pragma unroll
  for (int i = 0; i < 16; ++i) {
    int idx = t + i * 256;
    int r = idx >> 6, c = idx & 63;
    tl[c][r] = W[(size_t)(k0 + r) * 512 + n0 + c];
  }
  __syncthreads();
#pragma unroll
  for (int i = 0; i < 16; ++i) {
    int idx = t + i * 256;
    int r = idx >> 6, c = idx & 63;
    o[(size_t)(n0 + r) * 512 + k0 + c] = f2bf(tl[r][c]);
  }
}

// ---- bf16 MFMA GEMM, global_load_lds(16B), BK=64 via dual [BM][32] buffers ----
// MODE 0 (grid 768, BM=128): bm = bid&63, nz = bid>>6; q (scaled 1/8), k -> (B*H,N,64);
//         v -> transposed (B*H,64,N).
// MODE 1 (grid 512, BM=64):  bm = bid&127, bn = bid>>7; Wo; out f32 (B*N,512).
template <int MODE>
__global__ __launch_bounds__(256) void gemm_kernel(
    const unsigned short* __restrict__ A,
    const unsigned short* __restrict__ wt,
    const float* __restrict__ b0, const float* __restrict__ b1, const float* __restrict__ b2,
    void* __restrict__ outp) {
  constexpr int BM = MODE ? 64 : 128;
  constexpr int MI = MODE ? 2 : 4;
  const int bid = blockIdx.x;
  int bm, bn, z;
  if (MODE == 0) {
    bm = bid & 63;
    const int nz = bid >> 6;      // 0..11
    z = nz >> 2;
    bn = nz & 3;
  } else {
    bm = bid & 127;
    bn = bid >> 7;
    z = 0;
  }
  const int bm0 = bm * BM;
  const int bn0 = bn * 128;
  const unsigned short* W = wt + (size_t)z * 262144;
  const float* bias = (MODE == 0) ? ((z == 0) ? b0 : (z == 1) ? b1 : b2) : b0;

  __shared__ unsigned short As0[BM * 32];
  __shared__ unsigned short As1[BM * 32];
  __shared__ unsigned short Bs0[128 * 32];
  __shared__ unsigned short Bs1[128 * 32];

  const int t = threadIdx.x;
  const int lane = t & 63;
  const int wv = t >> 6;
  const int wr = wv >> 1, wc = wv & 1;
  const int l15 = lane & 15, l4 = lane >> 4;

  const int cr = lane >> 2;          // row within 16-row chunk
  const int cc = (lane & 3) * 8;     // col halves within 32

  const unsigned short* ApA;
  unsigned short *lA0a, *lA1a, *lA0b = nullptr, *lA1b = nullptr;
  const unsigned short* ApB = nullptr;
  if (MODE == 0) {
    ApA = A + (size_t)(bm0 + wv * 32 + cr) * 512 + cc;
    ApB = ApA + (size_t)16 * 512;
    lA0a = &As0[(wv * 2 + 0) * 512];
    lA0b = &As0[(wv * 2 + 1) * 512];
    lA1a = &As1[(wv * 2 + 0) * 512];
    lA1b = &As1[(wv * 2 + 1) * 512];
  } else {
    ApA = A + (size_t)(bm0 + wv * 16 + cr) * 512 + cc;
    lA0a = &As0[wv * 512];
    lA1a = &As1[wv * 512];
  }
  const unsigned short* BpA = W + (size_t)(bn0 + wv * 32 + cr) * 512 + cc;
  const unsigned short* BpB = BpA + (size_t)16 * 512;
  unsigned short* lB0a = &Bs0[(wv * 2 + 0) * 512];
  unsigned short* lB0b = &Bs0[(wv * 2 + 1) * 512];
  unsigned short* lB1a = &Bs1[(wv * 2 + 0) * 512];
  unsigned short* lB1b = &Bs1[(wv * 2 + 1) * 512];

  f32x4 acc[MI][4];
#pragma unroll
  for (int i = 0; i < MI; ++i)
#pragma unroll
    for (int j = 0; j < 4; ++j) acc[i][j] = (f32x4){0.f, 0.f, 0.f, 0.f};

  for (int kt = 0; kt < 512; kt += 64) {
    __syncthreads();
    GLOAD_LDS16(ApA + kt, lA0a);
    GLOAD_LDS16(ApA + kt + 32, lA1a);
    if (MODE == 0) {
      GLOAD_LDS16(ApB + kt, lA0b);
      GLOAD_LDS16(ApB + kt + 32, lA1b);
    }
    GLOAD_LDS16(BpA + kt, lB0a);
    GLOAD_LDS16(BpA + kt + 32, lB1a);
    GLOAD_LDS16(BpB + kt, lB0b);
    GLOAD_LDS16(BpB + kt + 32, lB1b);
    __syncthreads();
    bf16x8 af0[MI], af1[MI], bf0[4], bf1[4];
#pragma unroll
    for (int mi = 0; mi < MI; ++mi) {
      const int r = (MODE ? wr * 32 : wr * 64) + mi * 16 + l15;
      af0[mi] = *(const bf16x8*)&As0[r * 32 + l4 * 8];
      af1[mi] = *(const bf16x8*)&As1[r * 32 + l4 * 8];
    }
#pragma unroll
    for (int ni = 0; ni < 4; ++ni) {
      const int r = wc * 64 + ni * 16 + l15;
      bf0[ni] = *(const bf16x8*)&Bs0[r * 32 + l4 * 8];
      bf1[ni] = *(const bf16x8*)&Bs1[r * 32 + l4 * 8];
    }
#pragma unroll
    for (int mi = 0; mi < MI; ++mi)
#pragma unroll
      for (int ni = 0; ni < 4; ++ni) {
        acc[mi][ni] = __builtin_amdgcn_mfma_f32_16x16x32_bf16(af0[mi], bf0[ni], acc[mi][ni], 0, 0, 0);
        acc[mi][ni] = __builtin_amdgcn_mfma_f32_16x16x32_bf16(af1[mi], bf1[ni], acc[mi][ni], 0, 0, 0);
      }
  }

  const float sc = (MODE == 0 && z == 0) ? 0.125f : 1.0f;
#pragma unroll
  for (int mi = 0; mi < MI; ++mi) {
#pragma unroll
    for (int ni = 0; ni < 4; ++ni) {
      const int gn = bn0 + wc * 64 + ni * 16 + l15;
      const float bb = bias[gn];
      if (MODE == 0 && z == 2) {
        ushort4 o4;
        o4.x = f2bf(acc[mi][ni][0] + bb);
        o4.y = f2bf(acc[mi][ni][1] + bb);
        o4.z = f2bf(acc[mi][ni][2] + bb);
        o4.w = f2bf(acc[mi][ni][3] + bb);
        const int gm0 = bm0 + wr * 64 + mi * 16 + l4 * 4;
        const int b = gm0 >> 12;
        const int nn = gm0 & 4095;
        const int h = gn >> 6;
        const int dd = gn & 63;
        unsigned short* op = (unsigned short*)outp + (size_t)2 * 4194304;
        *(ushort4*)&op[((size_t)(b * NH + h) * HD + dd) * SEQ + nn] = o4;
      } else {
#pragma unroll
        for (int j = 0; j < 4; ++j) {
          const int gm = bm0 + (MODE ? wr * 32 : wr * 64) + mi * 16 + l4 * 4 + j;
          const float val = (acc[mi][ni][j] + bb) * sc;
          if (MODE == 0) {
            const int b = gm >> 12;
            const int nn = gm & 4095;
            const int h = gn >> 6;
            const int dd = gn & 63;
            unsigned short* op = (unsigned short*)outp + (size_t)z * 4194304;
            op[(((size_t)(b * NH + h) * SEQ) + nn) * HD + dd] = f2bf(val);
          } else {
            float* op = (float*)outp;
            op[(size_t)gm * 512 + gn] = val;
          }
        }
      }
    }
  }
}

// ---- MFMA local attention ----
// 256 threads = 4 waves, wave = 16 queries. V fragments hoisted to registers
// at kernel entry (independent of QK/softmax -> latency hidden under them).
// QK^T banded strip (10 MFMAs), softmax in C-frag registers, normalized P ->
// f32 LDS strip (stride 100), PV (12 MFMAs), then attn_out stores straight
// from registers (off the critical path).
__global__ __launch_bounds__(256) void attn_kernel(
    const unsigned short* __restrict__ qb, const unsigned short* __restrict__ kb,
    const unsigned short* __restrict__ vt,
    float* __restrict__ attn_out, unsigned short* __restrict__ ctxb) {
  __shared__ float P[4][16][100];     // cols 0..79 = scores, 80..95 zero pad
  const int t = threadIdx.x;
  const int lane = t & 63;
  const int wv = t >> 6;              // 0..3
  const int l15 = lane & 15;
  const int g = lane >> 4;
  const int bh = blockIdx.y;
  const int n0 = blockIdx.x * 64;
  const int q0 = n0 + wv * 16;
  const size_t qkbase = (size_t)bh * SEQ * HD;

  // ---- hoisted independent loads: q fragments + all 12 V fragments ----
  bf16x8 aq[2];
#pragma unroll
  for (int kc = 0; kc < 2; ++kc)
    aq[kc] = *(const bf16x8*)&qb[qkbase + (size_t)(q0 + l15) * HD + kc * 32 + g * 8];

  bf16x8 bv[3][4];
#pragma unroll
  for (int kc = 0; kc < 3; ++kc) {
    const int nb = q0 - 32 + kc * 32 + g * 8;   // multiple of 8: chunk all-in or all-out
    const bool inr = (nb >= 0 && nb < SEQ);
    const int nsafe = inr ? nb : 0;
#pragma unroll
    for (int dt = 0; dt < 4; ++dt) {
      bf16x8 v = *(const bf16x8*)&vt[((size_t)bh * HD + dt * 16 + l15) * SEQ + nsafe];
      bv[kc][dt] = inr ? v : (bf16x8){0, 0, 0, 0, 0, 0, 0, 0};
    }
  }

  // ---- QK^T: S[i][c], c in [0,80), k-row = q0-32+c  (q pre-scaled by 1/8) ----
  f32x4 accs[5];
#pragma unroll
  for (int tt = 0; tt < 5; ++tt) accs[tt] = (f32x4){0.f, 0.f, 0.f, 0.f};

#pragma unroll
  for (int tt = 0; tt < 5; ++tt) {
    const int krow = q0 - 32 + tt * 16 + l15;
    bf16x8 bk0 = (bf16x8){0, 0, 0, 0, 0, 0, 0, 0};
    bf16x8 bk1 = bk0;
    if (krow >= 0 && krow < SEQ) {
      bk0 = *(const bf16x8*)&kb[qkbase + (size_t)krow * HD + g * 8];
      bk1 = *(const bf16x8*)&kb[qkbase + (size_t)krow * HD + 32 + g * 8];
    }
    accs[tt] = __builtin_amdgcn_mfma_f32_16x16x32_bf16(aq[0], bk0, accs[tt], 0, 0, 0);
    accs[tt] = __builtin_amdgcn_mfma_f32_16x16x32_bf16(aq[1], bk1, accs[tt], 0, 0, 0);
  }

  // ---- softmax over w = c - i in [0,64]; C layout: col = 16tt+l15, row = 4g+j ----
#pragma unroll
  for (int tt = 0; tt < 5; ++tt)
#pragma unroll
    for (int j = 0; j < 4; ++j) {
      const int w = tt * 16 + l15 - (4 * g + j);
      if (!(w >= 0 && w <= 64)) accs[tt][j] = -3.0e38f;
    }
  float mj[4], invj[4];
#pragma unroll
  for (int j = 0; j < 4; ++j) {
    float m = fmaxf(fmaxf(fmaxf(accs[0][j], accs[1][j]), fmaxf(accs[2][j], accs[3][j])), accs[4][j]);
#pragma unroll
    for (int o = 8; o; o >>= 1) m = fmaxf(m, __shfl_xor(m, o));
    mj[j] = m;
  }
#pragma unroll
  for (int tt = 0; tt < 5; ++tt)
#pragma unroll
    for (int j = 0; j < 4; ++j)
      accs[tt][j] = (accs[tt][j] > -1.0e38f) ? __expf(accs[tt][j] - mj[j]) : 0.f;
#pragma unroll
  for (int j = 0; j < 4; ++j) {
    float s = accs[0][j] + accs[1][j] + accs[2][j] + accs[3][j] + accs[4][j];
#pragma unroll
    for (int o = 8; o; o >>= 1) s += __shfl_xor(s, o);
    invj[j] = 1.f / s;
  }
  // normalize in registers (kept live for the direct attn_out stores)
#pragma unroll
  for (int tt = 0; tt < 5; ++tt)
#pragma unroll
    for (int j = 0; j < 4; ++j)
      accs[tt][j] *= invj[j];

  // P -> LDS (cols 0..79), zero pad cols 80..95
#pragma unroll
  for (int tt = 0; tt < 5; ++tt)
#pragma unroll
    for (int j = 0; j < 4; ++j)
      P[wv][4 * g + j][tt * 16 + l15] = accs[tt][j];
  {
    const int r = lane >> 2, c4 = lane & 3;
#pragma unroll
    for (int jj = 0; jj < 4; ++jj) P[wv][r][80 + c4 + 4 * jj] = 0.f;
  }

  // ---- PV: ctx[i][d] = sum_c P[i][c] * V[q0-32+c][d], V frags already in regs ----
  f32x4 accc[4];
#pragma unroll
  for (int dt = 0; dt < 4; ++dt) accc[dt] = (f32x4){0.f, 0.f, 0.f, 0.f};
#pragma unroll
  for (int kc = 0; kc < 3; ++kc) {
    const float4 p0 = *(const float4*)&P[wv][l15][kc * 32 + g * 8];
    const float4 p1 = *(const float4*)&P[wv][l15][kc * 32 + g * 8 + 4];
    bf16x8 pa;
    pa[0] = (short)f2bf(p0.x); pa[1] = (short)f2bf(p0.y);
    pa[2] = (short)f2bf(p0.z); pa[3] = (short)f2bf(p0.w);
    pa[4] = (short)f2bf(p1.x); pa[5] = (short)f2bf(p1.y);
    pa[6] = (short)f2bf(p1.z); pa[7] = (short)f2bf(p1.w);
#pragma unroll
    for (int dt = 0; dt < 4; ++dt)
      accc[dt] = __builtin_amdgcn_mfma_f32_16x16x32_bf16(pa, bv[kc][dt], accc[dt], 0, 0, 0);
  }
  const int b = bh >> 3, h = bh & 7;
#pragma unroll
  for (int dt = 0; dt < 4; ++dt)
#pragma unroll
    for (int j = 0; j < 4; ++j)
      ctxb[((size_t)(b * SEQ + q0 + 4 * g + j)) * DM + h * HD + dt * 16 + l15] = f2bf(accc[dt][j]);

  // ---- attn_out stores straight from registers (off the dependency chain) ----
  {
    const size_t abase = (size_t)bh * SEQ;
#pragma unroll
    for (int tt = 0; tt < 5; ++tt)
#pragma unroll
      for (int j = 0; j < 4; ++j) {
        const int i = 4 * g + j;
        const int w = tt * 16 + l15 - i;
        if (w >= 0 && w <= 64)
          attn_out[(abase + q0 + i) * WIN + w] = accs[tt][j];
      }
  }
}

extern "C" void kernel_launch(void* const* d_in, const int* in_sizes, int n_in,
                              void* d_out, int out_size, void* d_ws, size_t ws_size,
                              hipStream_t stream) {
  const float* x  = (const float*)d_in[0];
  const float* Wq = (const float*)d_in[1];
  const float* Wk = (const float*)d_in[2];
  const float* Wv = (const float*)d_in[3];
  const float* Wo = (const float*)d_in[4];
  const float* bq = (const float*)d_in[5];
  const float* bk = (const float*)d_in[6];
  const float* bv = (const float*)d_in[7];
  const float* bo = (const float*)d_in[8];

  float* out = (float*)d_out;                        // (B, N, 512) f32
  float* attn_out = out + (size_t)8192 * 512;        // (B, H, N, 65) f32

  char* ws = (char*)d_ws;
  unsigned short* xb   = (unsigned short*)ws;                       // 8,388,608 B
  unsigned short* wt   = (unsigned short*)(ws + 8388608);           // 2,097,152 B
  unsigned short* qkv  = (unsigned short*)(ws + 10485760);          // 25,165,824 B
  unsigned short* ctxb = (unsigned short*)(ws + 35651584);          // 8,388,608 B

  prep_kernel<<<dim3(4352), dim3(256), 0, stream>>>(x, xb, Wq, Wk, Wv, Wo, wt);
  gemm_kernel<0><<<dim3(768), dim3(256), 0, stream>>>(xb, wt, bq, bk, bv, (void*)qkv);
  attn_kernel<<<dim3(64, 16), dim3(256), 0, stream>>>(
      qkv, qkv + 4194304, qkv + 8388608, attn_out, ctxb);
  gemm_kernel<1><<<dim3(512), dim3(256), 0, stream>>>(ctxb, wt + 3 * 262144, bo, nullptr, nullptr, (void*)out);
}

// Round 10
// 66.216 us; speedup vs baseline: 1.2098x; 1.0227x over previous
//
#include <hip/hip_runtime.h>
#include <hip/hip_bf16.h>
#include <stdint.h>

#define SEQ 4096
#define DM 512
#define NH 8
#define HD 64
#define WIN 65

typedef __attribute__((ext_vector_type(8))) short bf16x8;
typedef __attribute__((ext_vector_type(4))) float f32x4;

#define GLOAD_LDS16(gp, lp)                                                 \
  __builtin_amdgcn_global_load_lds(                                         \
      (const __attribute__((address_space(1))) void*)(gp),                  \
      (__attribute__((address_space(3))) void*)(lp), 16, 0, 0)

__device__ __forceinline__ unsigned short f2bf(float f) {
  unsigned int u = __float_as_uint(f);
  u += 0x7FFFu + ((u >> 16) & 1u);
  return (unsigned short)(u >> 16);
}

// ---- fused prep: convert x (f32->bf16) and transpose+convert all 4 W ----
__global__ __launch_bounds__(256) void prep_kernel(
    const float* __restrict__ x, unsigned short* __restrict__ xb,
    const float* __restrict__ w0, const float* __restrict__ w1,
    const float* __restrict__ w2, const float* __restrict__ w3,
    unsigned short* __restrict__ wt) {
  __shared__ float tl[64][65];
  const int bid = blockIdx.x;
  const int t = threadIdx.x;
  if (bid < 4096) {
    const int i = bid * 256 + t;
    float4 v = ((const float4*)x)[i];
    ushort4 o;
    o.x = f2bf(v.x); o.y = f2bf(v.y); o.z = f2bf(v.z); o.w = f2bf(v.w);
    ((ushort4*)xb)[i] = o;
    return;
  }
  const int wtid = bid - 4096;          // [0,256)
  const int z = wtid >> 6;
  const int rem = wtid & 63;
  const int k0 = (rem >> 3) * 64;
  const int n0 = (rem & 7) * 64;
  const float* W = (z == 0) ? w0 : (z == 1) ? w1 : (z == 2) ? w2 : w3;
  unsigned short* o = wt + (size_t)z * 262144;
#pragma unroll
  for (int i = 0; i < 16; ++i) {
    int idx = t + i * 256;
    int r = idx >> 6, c = idx & 63;
    tl[c][r] = W[(size_t)(k0 + r) * 512 + n0 + c];
  }
  __syncthreads();
#pragma unroll
  for (int i = 0; i < 16; ++i) {
    int idx = t + i * 256;
    int r = idx >> 6, c = idx & 63;
    o[(size_t)(n0 + r) * 512 + k0 + c] = f2bf(tl[r][c]);
  }
}

// ---- bf16 MFMA GEMM, global_load_lds(16B), BK=64 dual buffers, LDS-staged
// coalesced epilogues (K-loop buffers and epilogue tile share one smem union).
// MODE 0 (grid 768, BM=128): bm = bid&63, nz = bid>>6; q (scaled 1/8), k -> (B*H,N,64);
//         v -> transposed (B*H,64,N) via direct (already-coalesced) path.
// MODE 1 (grid 512, BM=64):  bm = bid&127, bn = bid>>7; Wo; out f32 (B*N,512).
template <int MODE>
__global__ __launch_bounds__(256) void gemm_kernel(
    const unsigned short* __restrict__ A,
    const unsigned short* __restrict__ wt,
    const float* __restrict__ b0, const float* __restrict__ b1, const float* __restrict__ b2,
    void* __restrict__ outp) {
  constexpr int BM = MODE ? 64 : 128;
  constexpr int MI = MODE ? 2 : 4;
  const int bid = blockIdx.x;
  int bm, bn, z;
  if (MODE == 0) {
    bm = bid & 63;
    const int nz = bid >> 6;      // 0..11
    z = nz >> 2;
    bn = nz & 3;
  } else {
    bm = bid & 127;
    bn = bid >> 7;
    z = 0;
  }
  const int bm0 = bm * BM;
  const int bn0 = bn * 128;
  const unsigned short* W = wt + (size_t)z * 262144;
  const float* bias = (MODE == 0) ? ((z == 0) ? b0 : (z == 1) ? b1 : b2) : b0;

  // smem union: K-loop buffers (<=32KB) / epilogue tile (<=34816B)
  __shared__ __align__(16) unsigned char sm[34816];
  unsigned short* As0 = (unsigned short*)sm;                    // BM*32 shorts
  unsigned short* As1 = (unsigned short*)(sm + BM * 64);
  unsigned short* Bs0 = (unsigned short*)(sm + BM * 128);       // 128*32 shorts
  unsigned short* Bs1 = (unsigned short*)(sm + BM * 128 + 8192);

  const int t = threadIdx.x;
  const int lane = t & 63;
  const int wv = t >> 6;
  const int wr = wv >> 1, wc = wv & 1;
  const int l15 = lane & 15, l4 = lane >> 4;

  const int cr = lane >> 2;          // row within 16-row chunk
  const int cc = (lane & 3) * 8;     // col halves within 32

  const unsigned short* ApA;
  unsigned short *lA0a, *lA1a, *lA0b = nullptr, *lA1b = nullptr;
  const unsigned short* ApB = nullptr;
  if (MODE == 0) {
    ApA = A + (size_t)(bm0 + wv * 32 + cr) * 512 + cc;
    ApB = ApA + (size_t)16 * 512;
    lA0a = &As0[(wv * 2 + 0) * 512];
    lA0b = &As0[(wv * 2 + 1) * 512];
    lA1a = &As1[(wv * 2 + 0) * 512];
    lA1b = &As1[(wv * 2 + 1) * 512];
  } else {
    ApA = A + (size_t)(bm0 + wv * 16 + cr) * 512 + cc;
    lA0a = &As0[wv * 512];
    lA1a = &As1[wv * 512];
  }
  const unsigned short* BpA = W + (size_t)(bn0 + wv * 32 + cr) * 512 + cc;
  const unsigned short* BpB = BpA + (size_t)16 * 512;
  unsigned short* lB0a = &Bs0[(wv * 2 + 0) * 512];
  unsigned short* lB0b = &Bs0[(wv * 2 + 1) * 512];
  unsigned short* lB1a = &Bs1[(wv * 2 + 0) * 512];
  unsigned short* lB1b = &Bs1[(wv * 2 + 1) * 512];

  f32x4 acc[MI][4];
#pragma unroll
  for (int i = 0; i < MI; ++i)
#pragma unroll
    for (int j = 0; j < 4; ++j) acc[i][j] = (f32x4){0.f, 0.f, 0.f, 0.f};

  for (int kt = 0; kt < 512; kt += 64) {
    __syncthreads();
    GLOAD_LDS16(ApA + kt, lA0a);
    GLOAD_LDS16(ApA + kt + 32, lA1a);
    if (MODE == 0) {
      GLOAD_LDS16(ApB + kt, lA0b);
      GLOAD_LDS16(ApB + kt + 32, lA1b);
    }
    GLOAD_LDS16(BpA + kt, lB0a);
    GLOAD_LDS16(BpA + kt + 32, lB1a);
    GLOAD_LDS16(BpB + kt, lB0b);
    GLOAD_LDS16(BpB + kt + 32, lB1b);
    __syncthreads();
    bf16x8 af0[MI], af1[MI], bf0[4], bf1[4];
#pragma unroll
    for (int mi = 0; mi < MI; ++mi) {
      const int r = (MODE ? wr * 32 : wr * 64) + mi * 16 + l15;
      af0[mi] = *(const bf16x8*)&As0[r * 32 + l4 * 8];
      af1[mi] = *(const bf16x8*)&As1[r * 32 + l4 * 8];
    }
#pragma unroll
    for (int ni = 0; ni < 4; ++ni) {
      const int r = wc * 64 + ni * 16 + l15;
      bf0[ni] = *(const bf16x8*)&Bs0[r * 32 + l4 * 8];
      bf1[ni] = *(const bf16x8*)&Bs1[r * 32 + l4 * 8];
    }
#pragma unroll
    for (int mi = 0; mi < MI; ++mi)
#pragma unroll
      for (int ni = 0; ni < 4; ++ni) {
        acc[mi][ni] = __builtin_amdgcn_mfma_f32_16x16x32_bf16(af0[mi], bf0[ni], acc[mi][ni], 0, 0, 0);
        acc[mi][ni] = __builtin_amdgcn_mfma_f32_16x16x32_bf16(af1[mi], bf1[ni], acc[mi][ni], 0, 0, 0);
      }
  }

  if (MODE == 0 && z == 2) {
    // vt path: direct (already coalesced along n)
#pragma unroll
    for (int mi = 0; mi < MI; ++mi) {
#pragma unroll
      for (int ni = 0; ni < 4; ++ni) {
        const int gn = bn0 + wc * 64 + ni * 16 + l15;
        const float bb = bias[gn];
        ushort4 o4;
        o4.x = f2bf(acc[mi][ni][0] + bb);
        o4.y = f2bf(acc[mi][ni][1] + bb);
        o4.z = f2bf(acc[mi][ni][2] + bb);
        o4.w = f2bf(acc[mi][ni][3] + bb);
        const int gm0 = bm0 + wr * 64 + mi * 16 + l4 * 4;
        const int b = gm0 >> 12;
        const int nn = gm0 & 4095;
        const int h = gn >> 6;
        const int dd = gn & 63;
        unsigned short* op = (unsigned short*)outp + (size_t)2 * 4194304;
        *(ushort4*)&op[((size_t)(b * NH + h) * HD + dd) * SEQ + nn] = o4;
      }
    }
  } else if (MODE == 0) {
    // q/k: acc -> LDS [128][136] bf16 tile -> fully-coalesced 16KB-contig writes
    __syncthreads();
    unsigned short (*ct)[136] = (unsigned short(*)[136])sm;
    const float sc = (z == 0) ? 0.125f : 1.0f;
#pragma unroll
    for (int mi = 0; mi < MI; ++mi)
#pragma unroll
      for (int ni = 0; ni < 4; ++ni) {
        const int gn = bn0 + wc * 64 + ni * 16 + l15;
        const float bb = bias[gn];
#pragma unroll
        for (int j = 0; j < 4; ++j)
          ct[wr * 64 + mi * 16 + l4 * 4 + j][wc * 64 + ni * 16 + l15] =
              f2bf((acc[mi][ni][j] + bb) * sc);
      }
    __syncthreads();
    const int b = bm0 >> 12;
    const int nn0 = bm0 & 4095;
    unsigned short* op = (unsigned short*)outp + (size_t)z * 4194304 +
                         ((size_t)(b * NH + (bn0 >> 6)) * SEQ + nn0) * HD;
#pragma unroll
    for (int r = 0; r < 8; ++r) {
      const int idx = r * 256 + t;           // 0..2047
      const int hh = idx >> 10;              // 0..1 (head within tile)
      const int tok = (idx >> 3) & 127;
      const int part = idx & 7;
      *(uint4*)&op[(size_t)hh * SEQ * HD + (size_t)tok * HD + part * 8] =
          *(const uint4*)&ct[tok][hh * 64 + part * 8];
    }
  } else {
    // Wo: acc -> LDS [64][132] f32 tile -> coalesced float4 writes
    __syncthreads();
    float (*cf)[132] = (float(*)[132])sm;
#pragma unroll
    for (int mi = 0; mi < MI; ++mi)
#pragma unroll
      for (int ni = 0; ni < 4; ++ni) {
        const int gn = bn0 + wc * 64 + ni * 16 + l15;
        const float bb = bias[gn];
#pragma unroll
        for (int j = 0; j < 4; ++j)
          cf[wr * 32 + mi * 16 + l4 * 4 + j][wc * 64 + ni * 16 + l15] = acc[mi][ni][j] + bb;
      }
    __syncthreads();
    float* op = (float*)outp + (size_t)bm0 * 512 + bn0;
#pragma unroll
    for (int r = 0; r < 8; ++r) {
      const int idx = r * 256 + t;           // 0..2047
      const int tok = idx >> 5;              // 0..63
      const int part = idx & 31;
      *(float4*)&op[(size_t)tok * 512 + part * 4] = *(const float4*)&cf[tok][part * 4];
    }
  }
}

// ---- MFMA local attention ----
// 256 threads = 4 waves, wave = 16 queries. V fragments hoisted to registers;
// QK^T banded strip (10 MFMAs), softmax in C-frag registers, P -> f32 LDS,
// PV (12 MFMAs), ctxb via per-wave LDS re-layout -> full-line uint4 writes,
// attn_out straight from registers.
__global__ __launch_bounds__(256) void attn_kernel(
    const unsigned short* __restrict__ qb, const unsigned short* __restrict__ kb,
    const unsigned short* __restrict__ vt,
    float* __restrict__ attn_out, unsigned short* __restrict__ ctxb) {
  __shared__ float P[4][16][100];     // cols 0..79 = scores, 80..95 zero pad
  const int t = threadIdx.x;
  const int lane = t & 63;
  const int wv = t >> 6;              // 0..3
  const int l15 = lane & 15;
  const int g = lane >> 4;
  const int bh = blockIdx.y;
  const int n0 = blockIdx.x * 64;
  const int q0 = n0 + wv * 16;
  const size_t qkbase = (size_t)bh * SEQ * HD;

  // ---- hoisted independent loads: q fragments + all 12 V fragments ----
  bf16x8 aq[2];
#pragma unroll
  for (int kc = 0; kc < 2; ++kc)
    aq[kc] = *(const bf16x8*)&qb[qkbase + (size_t)(q0 + l15) * HD + kc * 32 + g * 8];

  bf16x8 bv[3][4];
#pragma unroll
  for (int kc = 0; kc < 3; ++kc) {
    const int nb = q0 - 32 + kc * 32 + g * 8;   // multiple of 8: chunk all-in or all-out
    const bool inr = (nb >= 0 && nb < SEQ);
    const int nsafe = inr ? nb : 0;
#pragma unroll
    for (int dt = 0; dt < 4; ++dt) {
      bf16x8 v = *(const bf16x8*)&vt[((size_t)bh * HD + dt * 16 + l15) * SEQ + nsafe];
      bv[kc][dt] = inr ? v : (bf16x8){0, 0, 0, 0, 0, 0, 0, 0};
    }
  }

  // ---- QK^T: S[i][c], c in [0,80), k-row = q0-32+c  (q pre-scaled by 1/8) ----
  f32x4 accs[5];
#pragma unroll
  for (int tt = 0; tt < 5; ++tt) accs[tt] = (f32x4){0.f, 0.f, 0.f, 0.f};

#pragma unroll
  for (int tt = 0; tt < 5; ++tt) {
    const int krow = q0 - 32 + tt * 16 + l15;
    bf16x8 bk0 = (bf16x8){0, 0, 0, 0, 0, 0, 0, 0};
    bf16x8 bk1 = bk0;
    if (krow >= 0 && krow < SEQ) {
      bk0 = *(const bf16x8*)&kb[qkbase + (size_t)krow * HD + g * 8];
      bk1 = *(const bf16x8*)&kb[qkbase + (size_t)krow * HD + 32 + g * 8];
    }
    accs[tt] = __builtin_amdgcn_mfma_f32_16x16x32_bf16(aq[0], bk0, accs[tt], 0, 0, 0);
    accs[tt] = __builtin_amdgcn_mfma_f32_16x16x32_bf16(aq[1], bk1, accs[tt], 0, 0, 0);
  }

  // ---- softmax over w = c - i in [0,64]; C layout: col = 16tt+l15, row = 4g+j ----
#pragma unroll
  for (int tt = 0; tt < 5; ++tt)
#pragma unroll
    for (int j = 0; j < 4; ++j) {
      const int w = tt * 16 + l15 - (4 * g + j);
      if (!(w >= 0 && w <= 64)) accs[tt][j] = -3.0e38f;
    }
  float mj[4], invj[4];
#pragma unroll
  for (int j = 0; j < 4; ++j) {
    float m = fmaxf(fmaxf(fmaxf(accs[0][j], accs[1][j]), fmaxf(accs[2][j], accs[3][j])), accs[4][j]);
#pragma unroll
    for (int o = 8; o; o >>= 1) m = fmaxf(m, __shfl_xor(m, o));
    mj[j] = m;
  }
#pragma unroll
  for (int tt = 0; tt < 5; ++tt)
#pragma unroll
    for (int j = 0; j < 4; ++j)
      accs[tt][j] = (accs[tt][j] > -1.0e38f) ? __expf(accs[tt][j] - mj[j]) : 0.f;
#pragma unroll
  for (int j = 0; j < 4; ++j) {
    float s = accs[0][j] + accs[1][j] + accs[2][j] + accs[3][j] + accs[4][j];
#pragma unroll
    for (int o = 8; o; o >>= 1) s += __shfl_xor(s, o);
    invj[j] = 1.f / s;
  }
  // normalize in registers (kept live for the direct attn_out stores)
#pragma unroll
  for (int tt = 0; tt < 5; ++tt)
#pragma unroll
    for (int j = 0; j < 4; ++j)
      accs[tt][j] *= invj[j];

  // P -> LDS (cols 0..79), zero pad cols 80..95
#pragma unroll
  for (int tt = 0; tt < 5; ++tt)
#pragma unroll
    for (int j = 0; j < 4; ++j)
      P[wv][4 * g + j][tt * 16 + l15] = accs[tt][j];
  {
    const int r = lane >> 2, c4 = lane & 3;
#pragma unroll
    for (int jj = 0; jj < 4; ++jj) P[wv][r][80 + c4 + 4 * jj] = 0.f;
  }

  // ---- PV: ctx[i][d] = sum_c P[i][c] * V[q0-32+c][d], V frags already in regs ----
  f32x4 accc[4];
#pragma unroll
  for (int dt = 0; dt < 4; ++dt) accc[dt] = (f32x4){0.f, 0.f, 0.f, 0.f};
#pragma unroll
  for (int kc = 0; kc < 3; ++kc) {
    const float4 p0 = *(const float4*)&P[wv][l15][kc * 32 + g * 8];
    const float4 p1 = *(const float4*)&P[wv][l15][kc * 32 + g * 8 + 4];
    bf16x8 pa;
    pa[0] = (short)f2bf(p0.x); pa[1] = (short)f2bf(p0.y);
    pa[2] = (short)f2bf(p0.z); pa[3] = (short)f2bf(p0.w);
    pa[4] = (short)f2bf(p1.x); pa[5] = (short)f2bf(p1.y);
    pa[6] = (short)f2bf(p1.z); pa[7] = (short)f2bf(p1.w);
#pragma unroll
    for (int dt = 0; dt < 4; ++dt)
      accc[dt] = __builtin_amdgcn_mfma_f32_16x16x32_bf16(pa, bv[kc][dt], accc[dt], 0, 0, 0);
  }

  // ---- ctxb via per-wave LDS re-layout (reuses P slice) -> uint4 line writes ----
  const int b = bh >> 3, h = bh & 7;
  {
    asm volatile("s_waitcnt lgkmcnt(0)" ::: "memory");   // P reads drained (WAR)
    unsigned short (*ctw)[72] = (unsigned short(*)[72])((unsigned char*)&P[wv][0][0]);
#pragma unroll
    for (int dt = 0; dt < 4; ++dt)
#pragma unroll
      for (int j = 0; j < 4; ++j)
        ctw[4 * g + j][dt * 16 + l15] = f2bf(accc[dt][j]);
    asm volatile("s_waitcnt lgkmcnt(0)" ::: "memory");   // writes visible (RAW)
    unsigned short* cp = &ctxb[((size_t)(b * SEQ + q0)) * DM + h * HD];
#pragma unroll
    for (int r = 0; r < 2; ++r) {
      const int idx = r * 64 + lane;     // 0..127: tok = idx>>3, part = idx&7
      const int tok = idx >> 3, part = idx & 7;
      *(uint4*)&cp[(size_t)tok * DM + part * 8] = *(const uint4*)&ctw[tok][part * 8];
    }
  }

  // ---- attn_out stores straight from registers (off the dependency chain) ----
  {
    const size_t abase = (size_t)bh * SEQ;
#pragma unroll
    for (int tt = 0; tt < 5; ++tt)
#pragma unroll
      for (int j = 0; j < 4; ++j) {
        const int i = 4 * g + j;
        const int w = tt * 16 + l15 - i;
        if (w >= 0 && w <= 64)
          attn_out[(abase + q0 + i) * WIN + w] = accs[tt][j];
      }
  }
}

extern "C" void kernel_launch(void* const* d_in, const int* in_sizes, int n_in,
                              void* d_out, int out_size, void* d_ws, size_t ws_size,
                              hipStream_t stream) {
  const float* x  = (const float*)d_in[0];
  const float* Wq = (const float*)d_in[1];
  const float* Wk = (const float*)d_in[2];
  const float* Wv = (const float*)d_in[3];
  const float* Wo = (const float*)d_in[4];
  const float* bq = (const float*)d_in[5];
  const float* bk = (const float*)d_in[6];
  const float* bv = (const float*)d_in[7];
  const float* bo = (const float*)d_in[8];

  float* out = (float*)d_out;                        // (B, N, 512) f32
  float* attn_out = out + (size_t)8192 * 512;        // (B, H, N, 65) f32

  char* ws = (char*)d_ws;
  unsigned short* xb   = (unsigned short*)ws;                       // 8,388,608 B
  unsigned short* wt   = (unsigned short*)(ws + 8388608);           // 2,097,152 B
  unsigned short* qkv  = (unsigned short*)(ws + 10485760);          // 25,165,824 B
  unsigned short* ctxb = (unsigned short*)(ws + 35651584);          // 8,388,608 B

  prep_kernel<<<dim3(4352), dim3(256), 0, stream>>>(x, xb, Wq, Wk, Wv, Wo, wt);
  gemm_kernel<0><<<dim3(768), dim3(256), 0, stream>>>(xb, wt, bq, bk, bv, (void*)qkv);
  attn_kernel<<<dim3(64, 16), dim3(256), 0, stream>>>(
      qkv, qkv + 4194304, qkv + 8388608, attn_out, ctxb);
  gemm_kernel<1><<<dim3(512), dim3(256), 0, stream>>>(ctxb, wt + 3 * 262144, bo, nullptr, nullptr, (void*)out);
}